// Round 17
// baseline (101.343 us; speedup 1.0000x reference)
//
#include <hip/hip_runtime.h>
#include <hip/hip_bf16.h>
#include <math.h>

// Shapes (fixed by reference)
#define B_ 4
#define L_ 256
#define H_ 768
#define P_ 32896   // L*(L+1)/2
#define N_ 1536    // 2*H
#define K_ 768
#define M_ 1024    // B*L

typedef __attribute__((ext_vector_type(4))) float f32x4;
typedef __attribute__((ext_vector_type(8))) short s16x8;
typedef const __attribute__((address_space(1))) void* gptr_t;
typedef __attribute__((address_space(3))) void* sptr_t;

__device__ __forceinline__ unsigned pack_bf16(float x, float y) {
    __hip_bfloat16 hx = __float2bfloat16(x);   // RTN
    __hip_bfloat16 hy = __float2bfloat16(y);
    const unsigned short ux = *(const unsigned short*)&hx;
    const unsigned short uy = *(const unsigned short*)&hy;
    return (unsigned)ux | ((unsigned)uy << 16);
}

// ---------------------------------------------------------------------------
// Stage 0: fp32 -> bf16 conversion (memory-bound, ~12 MB traffic).
// ---------------------------------------------------------------------------
__global__ __launch_bounds__(256) void convert_to_bf16(
        const float* __restrict__ A, const float* __restrict__ W,
        unsigned short* __restrict__ Abf, unsigned short* __restrict__ Wbf) {
    const int idx = blockIdx.x * 256 + threadIdx.x;   // float4 index
    const int nA4 = (M_ * K_) / 4;                    // 196608
    const int nW4 = (H_ * N_) / 4;                    // 294912
    if (idx < nA4) {
        const float4 v = ((const float4*)A)[idx];
        ((uint2*)Abf)[idx] = make_uint2(pack_bf16(v.x, v.y), pack_bf16(v.z, v.w));
    } else if (idx < nA4 + nW4) {
        const int wi = idx - nA4;
        const int h  = wi / 384;          // 384 float4 per W row
        const int c  = (wi % 384) * 4;
        const float4 v = ((const float4*)W)[wi];
        const int n = h + ((c >= 768) ? 768 : 0);
        const int k = (c >= 768) ? (c - 768) : c;
        *(uint2*)(Wbf + (size_t)n * K_ + k) =
            make_uint2(pack_bf16(v.x, v.y), pack_bf16(v.z, v.w));
    }
}

// ---------------------------------------------------------------------------
// Stage 1: bf16 MFMA GEMM, double-buffered global_load_lds staging, K-split
// via blockIdx.z (Z=2: 768 blocks = 3/CU, 6 serial K-steps each). Bias folded
// into kz==0 partial.
// ---------------------------------------------------------------------------
__global__ __launch_bounds__(256) void gemm_uv_bf16(
        const unsigned short* __restrict__ Abf,
        const unsigned short* __restrict__ Wbf,
        const float* __restrict__ bias, float* __restrict__ T) {
    __shared__ __align__(16) char As[2][64 * 128];
    __shared__ __align__(16) char Bs[2][64 * 128];

    const int tid  = threadIdx.x;
    const int bm   = blockIdx.x * 64;
    const int bn   = blockIdx.y * 64;
    const int kz   = blockIdx.z;
    const int nst  = 12 / gridDim.z;     // K-steps per block (12 or 6)
    const int koff = kz * nst * 64;
    float* Tout = T + (size_t)kz * M_ * N_;

    const int lane = tid & 63;
    const int wave = tid >> 6;
    const int wm  = (wave & 1) * 32;
    const int wn  = (wave >> 1) * 32;
    const int l15 = lane & 15;
    const int l4  = lane >> 4;

    const int rl = lane >> 3;
    const int cc = lane & 7;
    const int srow0 = wave * 16;
    const int r0 = srow0 + rl;
    const int r1 = srow0 + 8 + rl;
    const int cp0 = cc ^ (r0 & 7);
    const int cp1 = cc ^ (r1 & 7);
    const unsigned short* a0p = Abf + (size_t)(bm + r0) * K_ + koff + cp0 * 8;
    const unsigned short* a1p = Abf + (size_t)(bm + r1) * K_ + koff + cp1 * 8;
    const unsigned short* w0p = Wbf + (size_t)(bn + r0) * K_ + koff + cp0 * 8;
    const unsigned short* w1p = Wbf + (size_t)(bn + r1) * K_ + koff + cp1 * 8;

    f32x4 acc[2][2] = {};

#define STAGE(bb, kt)                                                        \
    do {                                                                     \
        __builtin_amdgcn_global_load_lds((gptr_t)(a0p + (kt)),               \
            (sptr_t)(As[bb] + srow0 * 128), 16, 0, 0);                       \
        __builtin_amdgcn_global_load_lds((gptr_t)(w0p + (kt)),               \
            (sptr_t)(Bs[bb] + srow0 * 128), 16, 0, 0);                       \
        __builtin_amdgcn_global_load_lds((gptr_t)(a1p + (kt)),               \
            (sptr_t)(As[bb] + (srow0 + 8) * 128), 16, 0, 0);                 \
        __builtin_amdgcn_global_load_lds((gptr_t)(w1p + (kt)),               \
            (sptr_t)(Bs[bb] + (srow0 + 8) * 128), 16, 0, 0);                 \
    } while (0)

    STAGE(0, 0);
    __syncthreads();

    for (int t = 0; t < nst; ++t) {
        const int cur = t & 1;
        if (t + 1 < nst) STAGE(cur ^ 1, (t + 1) * 64);   // early issue

        const char* pA = As[cur];
        const char* pB = Bs[cur];
#pragma unroll
        for (int ks = 0; ks < 2; ++ks) {
            s16x8 af[2], bf[2];
#pragma unroll
            for (int mi = 0; mi < 2; ++mi) {
                const int row = wm + mi * 16 + l15;
                const int chunk = (ks * 4 + l4) ^ (row & 7);
                af[mi] = *(const s16x8*)(pA + row * 128 + chunk * 16);
            }
#pragma unroll
            for (int ni = 0; ni < 2; ++ni) {
                const int row = wn + ni * 16 + l15;
                const int chunk = (ks * 4 + l4) ^ (row & 7);
                bf[ni] = *(const s16x8*)(pB + row * 128 + chunk * 16);
            }
#pragma unroll
            for (int mi = 0; mi < 2; ++mi)
#pragma unroll
                for (int ni = 0; ni < 2; ++ni)
                    acc[mi][ni] = __builtin_amdgcn_mfma_f32_16x16x32_bf16(
                        af[mi], bf[ni], acc[mi][ni], 0, 0, 0);
        }
        __syncthreads();
    }
#undef STAGE

#pragma unroll
    for (int mi = 0; mi < 2; ++mi)
#pragma unroll
        for (int ni = 0; ni < 2; ++ni) {
            const int gm0 = bm + wm + mi * 16 + l4 * 4;
            const int gn  = bn + wn + ni * 16 + l15;
            const float badd = (kz == 0 && gn < H_) ? bias[gn] : 0.0f;
#pragma unroll
            for (int r = 0; r < 4; ++r)
                Tout[(size_t)(gm0 + r) * N_ + gn] = acc[mi][ni][r] + badd;
        }
}

// ---------------------------------------------------------------------------
// Fallback GEMM (fp32 inputs) if ws too small for bf16 scratch.
// ---------------------------------------------------------------------------
__global__ __launch_bounds__(256) void gemm_uv_mfma(
        const float* __restrict__ A, const float* __restrict__ W,
        const float* __restrict__ bias, float* __restrict__ T) {
    __shared__ __align__(16) char As[64 * 128];
    __shared__ __align__(16) char Bs[64 * 128];

    const int tid = threadIdx.x;
    const int bm = blockIdx.x * 64;
    const int bn = blockIdx.y * 64;
    const int lane = tid & 63;
    const int wave = tid >> 6;

    const int sr = tid >> 4;
    const int sk = (tid & 15) * 4;
    const float* wbase = (bn < H_) ? (W + (size_t)bn * N_)
                                   : (W + (size_t)(bn - H_) * N_ + H_);

    const int wm = (wave & 1) * 32;
    const int wn = (wave >> 1) * 32;
    const int l15 = lane & 15;
    const int l4  = lane >> 4;

    f32x4 acc[2][2] = {};

    for (int kt = 0; kt < K_; kt += 64) {
        __syncthreads();
#pragma unroll
        for (int ph = 0; ph < 4; ++ph) {
            const int row = ph * 16 + sr;
            const float4 av = *(const float4*)(A + (size_t)(bm + row) * K_ + kt + sk);
            const float4 bv = *(const float4*)(wbase + (size_t)row * N_ + kt + sk);
            const int chunk = sk >> 3;
            const int sub   = (sk & 4) ? 8 : 0;
            const int boff  = row * 128 + ((chunk ^ (row & 7)) * 16) + sub;
            *(uint2*)(As + boff) = make_uint2(pack_bf16(av.x, av.y), pack_bf16(av.z, av.w));
            *(uint2*)(Bs + boff) = make_uint2(pack_bf16(bv.x, bv.y), pack_bf16(bv.z, bv.w));
        }
        __syncthreads();
#pragma unroll
        for (int ks = 0; ks < 2; ++ks) {
            s16x8 af[2], bf[2];
#pragma unroll
            for (int mi = 0; mi < 2; ++mi) {
                const int row = wm + mi * 16 + l15;
                const int chunk = (ks * 4 + l4) ^ (row & 7);
                af[mi] = *(const s16x8*)(As + row * 128 + chunk * 16);
            }
#pragma unroll
            for (int ni = 0; ni < 2; ++ni) {
                const int row = wn + ni * 16 + l15;
                const int chunk = (ks * 4 + l4) ^ (row & 7);
                bf[ni] = *(const s16x8*)(Bs + row * 128 + chunk * 16);
            }
#pragma unroll
            for (int mi = 0; mi < 2; ++mi)
#pragma unroll
                for (int ni = 0; ni < 2; ++ni)
                    acc[mi][ni] = __builtin_amdgcn_mfma_f32_16x16x32_bf16(
                        af[mi], bf[ni], acc[mi][ni], 0, 0, 0);
        }
    }

#pragma unroll
    for (int mi = 0; mi < 2; ++mi)
#pragma unroll
        for (int ni = 0; ni < 2; ++ni) {
            const int gm0 = bm + wm + mi * 16 + l4 * 4;
            const int gn  = bn + wn + ni * 16 + l15;
            const float badd = (gn < H_) ? bias[gn] : 0.0f;
#pragma unroll
            for (int r = 0; r < 4; ++r)
                T[(size_t)(gm0 + r) * N_ + gn] = acc[mi][ni][r] + badd;
        }
}

// tanh(x) = 1 - 2/(exp2(2*log2e*x)+1); exact at +-inf. 5 VALU ops.
__device__ __forceinline__ float fast_tanh(float x) {
    const float e = __builtin_amdgcn_exp2f(x * 2.885390081777926815f);
    const float r = __builtin_amdgcn_rcpf(e + 1.0f);
    return fmaf(-2.0f, r, 1.0f);
}

__device__ __forceinline__ f32x4 tanh4(f32x4 u, f32x4 v) {
    f32x4 o;
    o.x = fast_tanh(u.x + v.x);
    o.y = fast_tanh(u.y + v.y);
    o.z = fast_tanh(u.z + v.z);
    o.w = fast_tanh(u.w + v.w);
    return o;
}

// ---------------------------------------------------------------------------
// Epilogue v7 = R16 quad dense front with REGULAR stores (A/B vs R16's NT in
// the dense-front regime): dense front + L2 write-combining is fillBuffer's
// 6.9 TB/s mechanism; NT bypasses L2 and sends uncombined 16B stores to the
// fabric. R8's "NT wins" was measured in the old scattered-stream structure.
// ---------------------------------------------------------------------------
#define NROWS_ (B_ * P_)    // 131584
#define NQUAD_ (NROWS_ / 4) // 32896
#define EGRID_ 1024

__global__ __launch_bounds__(192) void handshake_epilogue_quad2(
        const float* __restrict__ T,
        float* __restrict__ out) {
    const int h = threadIdx.x * 4;      // 192 threads * 4 = 768 floats/row
    const float* __restrict__ T1 = T + (size_t)M_ * N_;

    for (int q = blockIdx.x; q < NQUAD_; q += EGRID_) {
        const int rbase = q * 4;
        const int b  = rbase / P_;       // same b for all 4 rows (4 | P_)
        const int p0 = rbase - b * P_;

        const float Df = (float)(263169 - 8 * p0);   // exact in fp32
        int i = (int)((513.0f - __builtin_sqrtf(Df)) * 0.5f);
        if ((i + 1) * (513 - (i + 1)) / 2 <= p0) ++i;
        if (i * (513 - i) / 2 > p0) --i;
        int j = p0 - i * (513 - i) / 2 + i;          // i <= j < 256

        const size_t tb = (size_t)b * L_ * N_;
        f32x4 u = *(const f32x4*)(T + tb + (size_t)i * N_ + h)
                + *(const f32x4*)(T1 + tb + (size_t)i * N_ + h);
        float* orow = out + (size_t)rbase * H_ + h;

#pragma unroll
        for (int k = 0; k < 4; ++k) {
            const f32x4 v = *(const f32x4*)(T + tb + (size_t)j * N_ + H_ + h)
                          + *(const f32x4*)(T1 + tb + (size_t)j * N_ + H_ + h);
            *(f32x4*)orow = tanh4(u, v);             // regular store
            orow += H_;
            ++j;
            if (j == 256) {              // block-uniform branch
                ++i; j = i;
                u = *(const f32x4*)(T + tb + (size_t)i * N_ + h)
                  + *(const f32x4*)(T1 + tb + (size_t)i * N_ + h);
            }
        }
    }
}

// Single-T epilogue (fallback path), regular stores.
__global__ __launch_bounds__(192) void handshake_epilogue_quad(
        const float* __restrict__ T,
        float* __restrict__ out) {
    const int h = threadIdx.x * 4;

    for (int q = blockIdx.x; q < NQUAD_; q += EGRID_) {
        const int rbase = q * 4;
        const int b  = rbase / P_;
        const int p0 = rbase - b * P_;

        const float Df = (float)(263169 - 8 * p0);
        int i = (int)((513.0f - __builtin_sqrtf(Df)) * 0.5f);
        if ((i + 1) * (513 - (i + 1)) / 2 <= p0) ++i;
        if (i * (513 - i) / 2 > p0) --i;
        int j = p0 - i * (513 - i) / 2 + i;

        const float* Tb = T + (size_t)b * L_ * N_;
        f32x4 u = *(const f32x4*)(Tb + (size_t)i * N_ + h);
        float* orow = out + (size_t)rbase * H_ + h;

#pragma unroll
        for (int k = 0; k < 4; ++k) {
            const f32x4 v = *(const f32x4*)(Tb + (size_t)j * N_ + H_ + h);
            *(f32x4*)orow = tanh4(u, v);             // regular store
            orow += H_;
            ++j;
            if (j == 256) {
                ++i; j = i;
                u = *(const f32x4*)(Tb + (size_t)i * N_ + h);
            }
        }
    }
}

extern "C" void kernel_launch(void* const* d_in, const int* in_sizes, int n_in,
                              void* d_out, int out_size, void* d_ws, size_t ws_size,
                              hipStream_t stream) {
    const float* seq  = (const float*)d_in[0];   // (B, L, H) fp32
    const float* W    = (const float*)d_in[1];   // (H, 2H) fp32
    const float* bias = (const float*)d_in[2];   // (H,) fp32
    float* out = (float*)d_out;                  // (B, P, H) fp32

    char* ws = (char*)d_ws;
    float* T = (float*)ws;
    const size_t T_BYTES = (size_t)M_ * N_ * 4;              // 6.29 MB
    const size_t AB_BYTES = (size_t)M_ * K_ * 2;             // 1.57 MB
    const size_t WB_BYTES = (size_t)K_ * N_ * 2;             // 2.36 MB
    const size_t NEED2 = 2 * T_BYTES + AB_BYTES + WB_BYTES;  // 16.5 MB
    const size_t NEED1 = T_BYTES + AB_BYTES + WB_BYTES;      // 10.2 MB

    if (ws_size >= NEED2) {
        unsigned short* Abf = (unsigned short*)(ws + 2 * T_BYTES);
        unsigned short* Wbf = (unsigned short*)(ws + 2 * T_BYTES + AB_BYTES);
        convert_to_bf16<<<1920, 256, 0, stream>>>(seq, W, Abf, Wbf);
        dim3 g1(M_ / 64, N_ / 64, 2);            // 768 blocks, K-split 2
        gemm_uv_bf16<<<g1, 256, 0, stream>>>(Abf, Wbf, bias, T);
        handshake_epilogue_quad2<<<EGRID_, 192, 0, stream>>>(T, out);
    } else if (ws_size >= NEED1) {
        unsigned short* Abf = (unsigned short*)(ws + T_BYTES);
        unsigned short* Wbf = (unsigned short*)(ws + T_BYTES + AB_BYTES);
        convert_to_bf16<<<1920, 256, 0, stream>>>(seq, W, Abf, Wbf);
        dim3 g1(M_ / 64, N_ / 64, 1);            // 384 blocks, no split
        gemm_uv_bf16<<<g1, 256, 0, stream>>>(Abf, Wbf, bias, T);
        handshake_epilogue_quad<<<EGRID_, 192, 0, stream>>>(T, out);
    } else {
        dim3 g1(M_ / 64, N_ / 64);
        gemm_uv_mfma<<<g1, 256, 0, stream>>>(seq, W, bias, T);
        handshake_epilogue_quad<<<EGRID_, 192, 0, stream>>>(T, out);
    }
}

// Round 18
// 90.750 us; speedup vs baseline: 1.1167x; 1.1167x over previous
//
#include <hip/hip_runtime.h>
#include <hip/hip_bf16.h>
#include <math.h>

// Shapes (fixed by reference)
#define B_ 4
#define L_ 256
#define H_ 768
#define P_ 32896   // L*(L+1)/2
#define N_ 1536    // 2*H
#define K_ 768
#define M_ 1024    // B*L

typedef __attribute__((ext_vector_type(4))) float f32x4;
typedef __attribute__((ext_vector_type(8))) short s16x8;
typedef const __attribute__((address_space(1))) void* gptr_t;
typedef __attribute__((address_space(3))) void* sptr_t;

__device__ __forceinline__ unsigned pack_bf16(float x, float y) {
    __hip_bfloat16 hx = __float2bfloat16(x);   // RTN
    __hip_bfloat16 hy = __float2bfloat16(y);
    const unsigned short ux = *(const unsigned short*)&hx;
    const unsigned short uy = *(const unsigned short*)&hy;
    return (unsigned)ux | ((unsigned)uy << 16);
}

// ---------------------------------------------------------------------------
// Stage 0: fp32 -> bf16 conversion (memory-bound, ~12 MB traffic).
// ---------------------------------------------------------------------------
__global__ __launch_bounds__(256) void convert_to_bf16(
        const float* __restrict__ A, const float* __restrict__ W,
        unsigned short* __restrict__ Abf, unsigned short* __restrict__ Wbf) {
    const int idx = blockIdx.x * 256 + threadIdx.x;   // float4 index
    const int nA4 = (M_ * K_) / 4;                    // 196608
    const int nW4 = (H_ * N_) / 4;                    // 294912
    if (idx < nA4) {
        const float4 v = ((const float4*)A)[idx];
        ((uint2*)Abf)[idx] = make_uint2(pack_bf16(v.x, v.y), pack_bf16(v.z, v.w));
    } else if (idx < nA4 + nW4) {
        const int wi = idx - nA4;
        const int h  = wi / 384;          // 384 float4 per W row
        const int c  = (wi % 384) * 4;
        const float4 v = ((const float4*)W)[wi];
        const int n = h + ((c >= 768) ? 768 : 0);
        const int k = (c >= 768) ? (c - 768) : c;
        *(uint2*)(Wbf + (size_t)n * K_ + k) =
            make_uint2(pack_bf16(v.x, v.y), pack_bf16(v.z, v.w));
    }
}

// ---------------------------------------------------------------------------
// Stage 1: bf16 MFMA GEMM, double-buffered global_load_lds staging, K-split
// via blockIdx.z (Z=2: 768 blocks = 3/CU, 6 serial K-steps each). Bias folded
// into kz==0 partial.
// ---------------------------------------------------------------------------
__global__ __launch_bounds__(256) void gemm_uv_bf16(
        const unsigned short* __restrict__ Abf,
        const unsigned short* __restrict__ Wbf,
        const float* __restrict__ bias, float* __restrict__ T) {
    __shared__ __align__(16) char As[2][64 * 128];
    __shared__ __align__(16) char Bs[2][64 * 128];

    const int tid  = threadIdx.x;
    const int bm   = blockIdx.x * 64;
    const int bn   = blockIdx.y * 64;
    const int kz   = blockIdx.z;
    const int nst  = 12 / gridDim.z;     // K-steps per block (12 or 6)
    const int koff = kz * nst * 64;
    float* Tout = T + (size_t)kz * M_ * N_;

    const int lane = tid & 63;
    const int wave = tid >> 6;
    const int wm  = (wave & 1) * 32;
    const int wn  = (wave >> 1) * 32;
    const int l15 = lane & 15;
    const int l4  = lane >> 4;

    const int rl = lane >> 3;
    const int cc = lane & 7;
    const int srow0 = wave * 16;
    const int r0 = srow0 + rl;
    const int r1 = srow0 + 8 + rl;
    const int cp0 = cc ^ (r0 & 7);
    const int cp1 = cc ^ (r1 & 7);
    const unsigned short* a0p = Abf + (size_t)(bm + r0) * K_ + koff + cp0 * 8;
    const unsigned short* a1p = Abf + (size_t)(bm + r1) * K_ + koff + cp1 * 8;
    const unsigned short* w0p = Wbf + (size_t)(bn + r0) * K_ + koff + cp0 * 8;
    const unsigned short* w1p = Wbf + (size_t)(bn + r1) * K_ + koff + cp1 * 8;

    f32x4 acc[2][2] = {};

#define STAGE(bb, kt)                                                        \
    do {                                                                     \
        __builtin_amdgcn_global_load_lds((gptr_t)(a0p + (kt)),               \
            (sptr_t)(As[bb] + srow0 * 128), 16, 0, 0);                       \
        __builtin_amdgcn_global_load_lds((gptr_t)(w0p + (kt)),               \
            (sptr_t)(Bs[bb] + srow0 * 128), 16, 0, 0);                       \
        __builtin_amdgcn_global_load_lds((gptr_t)(a1p + (kt)),               \
            (sptr_t)(As[bb] + (srow0 + 8) * 128), 16, 0, 0);                 \
        __builtin_amdgcn_global_load_lds((gptr_t)(w1p + (kt)),               \
            (sptr_t)(Bs[bb] + (srow0 + 8) * 128), 16, 0, 0);                 \
    } while (0)

    STAGE(0, 0);
    __syncthreads();

    for (int t = 0; t < nst; ++t) {
        const int cur = t & 1;
        if (t + 1 < nst) STAGE(cur ^ 1, (t + 1) * 64);   // early issue

        const char* pA = As[cur];
        const char* pB = Bs[cur];
#pragma unroll
        for (int ks = 0; ks < 2; ++ks) {
            s16x8 af[2], bf[2];
#pragma unroll
            for (int mi = 0; mi < 2; ++mi) {
                const int row = wm + mi * 16 + l15;
                const int chunk = (ks * 4 + l4) ^ (row & 7);
                af[mi] = *(const s16x8*)(pA + row * 128 + chunk * 16);
            }
#pragma unroll
            for (int ni = 0; ni < 2; ++ni) {
                const int row = wn + ni * 16 + l15;
                const int chunk = (ks * 4 + l4) ^ (row & 7);
                bf[ni] = *(const s16x8*)(pB + row * 128 + chunk * 16);
            }
#pragma unroll
            for (int mi = 0; mi < 2; ++mi)
#pragma unroll
                for (int ni = 0; ni < 2; ++ni)
                    acc[mi][ni] = __builtin_amdgcn_mfma_f32_16x16x32_bf16(
                        af[mi], bf[ni], acc[mi][ni], 0, 0, 0);
        }
        __syncthreads();
    }
#undef STAGE

#pragma unroll
    for (int mi = 0; mi < 2; ++mi)
#pragma unroll
        for (int ni = 0; ni < 2; ++ni) {
            const int gm0 = bm + wm + mi * 16 + l4 * 4;
            const int gn  = bn + wn + ni * 16 + l15;
            const float badd = (kz == 0 && gn < H_) ? bias[gn] : 0.0f;
#pragma unroll
            for (int r = 0; r < 4; ++r)
                Tout[(size_t)(gm0 + r) * N_ + gn] = acc[mi][ni][r] + badd;
        }
}

// ---------------------------------------------------------------------------
// Fallback GEMM (fp32 inputs) if ws too small for bf16 scratch.
// ---------------------------------------------------------------------------
__global__ __launch_bounds__(256) void gemm_uv_mfma(
        const float* __restrict__ A, const float* __restrict__ W,
        const float* __restrict__ bias, float* __restrict__ T) {
    __shared__ __align__(16) char As[64 * 128];
    __shared__ __align__(16) char Bs[64 * 128];

    const int tid = threadIdx.x;
    const int bm = blockIdx.x * 64;
    const int bn = blockIdx.y * 64;
    const int lane = tid & 63;
    const int wave = tid >> 6;

    const int sr = tid >> 4;
    const int sk = (tid & 15) * 4;
    const float* wbase = (bn < H_) ? (W + (size_t)bn * N_)
                                   : (W + (size_t)(bn - H_) * N_ + H_);

    const int wm = (wave & 1) * 32;
    const int wn = (wave >> 1) * 32;
    const int l15 = lane & 15;
    const int l4  = lane >> 4;

    f32x4 acc[2][2] = {};

    for (int kt = 0; kt < K_; kt += 64) {
        __syncthreads();
#pragma unroll
        for (int ph = 0; ph < 4; ++ph) {
            const int row = ph * 16 + sr;
            const float4 av = *(const float4*)(A + (size_t)(bm + row) * K_ + kt + sk);
            const float4 bv = *(const float4*)(wbase + (size_t)row * N_ + kt + sk);
            const int chunk = sk >> 3;
            const int sub   = (sk & 4) ? 8 : 0;
            const int boff  = row * 128 + ((chunk ^ (row & 7)) * 16) + sub;
            *(uint2*)(As + boff) = make_uint2(pack_bf16(av.x, av.y), pack_bf16(av.z, av.w));
            *(uint2*)(Bs + boff) = make_uint2(pack_bf16(bv.x, bv.y), pack_bf16(bv.z, bv.w));
        }
        __syncthreads();
#pragma unroll
        for (int ks = 0; ks < 2; ++ks) {
            s16x8 af[2], bf[2];
#pragma unroll
            for (int mi = 0; mi < 2; ++mi) {
                const int row = wm + mi * 16 + l15;
                const int chunk = (ks * 4 + l4) ^ (row & 7);
                af[mi] = *(const s16x8*)(As + row * 128 + chunk * 16);
            }
#pragma unroll
            for (int ni = 0; ni < 2; ++ni) {
                const int row = wn + ni * 16 + l15;
                const int chunk = (ks * 4 + l4) ^ (row & 7);
                bf[ni] = *(const s16x8*)(Bs + row * 128 + chunk * 16);
            }
#pragma unroll
            for (int mi = 0; mi < 2; ++mi)
#pragma unroll
                for (int ni = 0; ni < 2; ++ni)
                    acc[mi][ni] = __builtin_amdgcn_mfma_f32_16x16x32_bf16(
                        af[mi], bf[ni], acc[mi][ni], 0, 0, 0);
        }
    }

#pragma unroll
    for (int mi = 0; mi < 2; ++mi)
#pragma unroll
        for (int ni = 0; ni < 2; ++ni) {
            const int gm0 = bm + wm + mi * 16 + l4 * 4;
            const int gn  = bn + wn + ni * 16 + l15;
            const float badd = (gn < H_) ? bias[gn] : 0.0f;
#pragma unroll
            for (int r = 0; r < 4; ++r)
                T[(size_t)(gm0 + r) * N_ + gn] = acc[mi][ni][r] + badd;
        }
}

// tanh(x) = 1 - 2/(exp2(2*log2e*x)+1); exact at +-inf. 5 VALU ops.
__device__ __forceinline__ float fast_tanh(float x) {
    const float e = __builtin_amdgcn_exp2f(x * 2.885390081777926815f);
    const float r = __builtin_amdgcn_rcpf(e + 1.0f);
    return fmaf(-2.0f, r, 1.0f);
}

__device__ __forceinline__ f32x4 tanh4(f32x4 u, f32x4 v) {
    f32x4 o;
    o.x = fast_tanh(u.x + v.x);
    o.y = fast_tanh(u.y + v.y);
    o.z = fast_tanh(u.z + v.z);
    o.w = fast_tanh(u.w + v.w);
    return o;
}

// ---------------------------------------------------------------------------
// Epilogue (R16 final): quad dense front + NT stores. A/B history: NT beats
// regular stores in BOTH scattered (R8: +8us) and dense-front (R17: +10us)
// regimes; read-volume/locality/VALU/occupancy all proven non-limiting
// (R12/R14/R15). 404 MB NT write stream at ~5.6 TB/s ~= 81% of the
// pure-store ceiling for this buffer; structural for read-compute-write.
// ---------------------------------------------------------------------------
#define NROWS_ (B_ * P_)    // 131584
#define NQUAD_ (NROWS_ / 4) // 32896
#define EGRID_ 1024

__global__ __launch_bounds__(192) void handshake_epilogue_quad2(
        const float* __restrict__ T,
        float* __restrict__ out) {
    const int h = threadIdx.x * 4;      // 192 threads * 4 = 768 floats/row
    const float* __restrict__ T1 = T + (size_t)M_ * N_;

    for (int q = blockIdx.x; q < NQUAD_; q += EGRID_) {
        const int rbase = q * 4;
        const int b  = rbase / P_;       // same b for all 4 rows (4 | P_)
        const int p0 = rbase - b * P_;

        const float Df = (float)(263169 - 8 * p0);   // exact in fp32
        int i = (int)((513.0f - __builtin_sqrtf(Df)) * 0.5f);
        if ((i + 1) * (513 - (i + 1)) / 2 <= p0) ++i;
        if (i * (513 - i) / 2 > p0) --i;
        int j = p0 - i * (513 - i) / 2 + i;          // i <= j < 256

        const size_t tb = (size_t)b * L_ * N_;
        f32x4 u = *(const f32x4*)(T + tb + (size_t)i * N_ + h)
                + *(const f32x4*)(T1 + tb + (size_t)i * N_ + h);
        float* orow = out + (size_t)rbase * H_ + h;

#pragma unroll
        for (int k = 0; k < 4; ++k) {
            const f32x4 v = *(const f32x4*)(T + tb + (size_t)j * N_ + H_ + h)
                          + *(const f32x4*)(T1 + tb + (size_t)j * N_ + H_ + h);
            __builtin_nontemporal_store(tanh4(u, v), (f32x4*)orow);
            orow += H_;
            ++j;
            if (j == 256) {              // block-uniform branch
                ++i; j = i;
                u = *(const f32x4*)(T + tb + (size_t)i * N_ + h)
                  + *(const f32x4*)(T1 + tb + (size_t)i * N_ + h);
            }
        }
    }
}

// Single-T epilogue (fallback path), NT stores.
__global__ __launch_bounds__(192) void handshake_epilogue_quad(
        const float* __restrict__ T,
        float* __restrict__ out) {
    const int h = threadIdx.x * 4;

    for (int q = blockIdx.x; q < NQUAD_; q += EGRID_) {
        const int rbase = q * 4;
        const int b  = rbase / P_;
        const int p0 = rbase - b * P_;

        const float Df = (float)(263169 - 8 * p0);
        int i = (int)((513.0f - __builtin_sqrtf(Df)) * 0.5f);
        if ((i + 1) * (513 - (i + 1)) / 2 <= p0) ++i;
        if (i * (513 - i) / 2 > p0) --i;
        int j = p0 - i * (513 - i) / 2 + i;

        const float* Tb = T + (size_t)b * L_ * N_;
        f32x4 u = *(const f32x4*)(Tb + (size_t)i * N_ + h);
        float* orow = out + (size_t)rbase * H_ + h;

#pragma unroll
        for (int k = 0; k < 4; ++k) {
            const f32x4 v = *(const f32x4*)(Tb + (size_t)j * N_ + H_ + h);
            __builtin_nontemporal_store(tanh4(u, v), (f32x4*)orow);
            orow += H_;
            ++j;
            if (j == 256) {
                ++i; j = i;
                u = *(const f32x4*)(Tb + (size_t)i * N_ + h);
            }
        }
    }
}

extern "C" void kernel_launch(void* const* d_in, const int* in_sizes, int n_in,
                              void* d_out, int out_size, void* d_ws, size_t ws_size,
                              hipStream_t stream) {
    const float* seq  = (const float*)d_in[0];   // (B, L, H) fp32
    const float* W    = (const float*)d_in[1];   // (H, 2H) fp32
    const float* bias = (const float*)d_in[2];   // (H,) fp32
    float* out = (float*)d_out;                  // (B, P, H) fp32

    char* ws = (char*)d_ws;
    float* T = (float*)ws;
    const size_t T_BYTES = (size_t)M_ * N_ * 4;              // 6.29 MB
    const size_t AB_BYTES = (size_t)M_ * K_ * 2;             // 1.57 MB
    const size_t WB_BYTES = (size_t)K_ * N_ * 2;             // 2.36 MB
    const size_t NEED2 = 2 * T_BYTES + AB_BYTES + WB_BYTES;  // 16.5 MB
    const size_t NEED1 = T_BYTES + AB_BYTES + WB_BYTES;      // 10.2 MB

    if (ws_size >= NEED2) {
        unsigned short* Abf = (unsigned short*)(ws + 2 * T_BYTES);
        unsigned short* Wbf = (unsigned short*)(ws + 2 * T_BYTES + AB_BYTES);
        convert_to_bf16<<<1920, 256, 0, stream>>>(seq, W, Abf, Wbf);
        dim3 g1(M_ / 64, N_ / 64, 2);            // 768 blocks, K-split 2
        gemm_uv_bf16<<<g1, 256, 0, stream>>>(Abf, Wbf, bias, T);
        handshake_epilogue_quad2<<<EGRID_, 192, 0, stream>>>(T, out);
    } else if (ws_size >= NEED1) {
        unsigned short* Abf = (unsigned short*)(ws + T_BYTES);
        unsigned short* Wbf = (unsigned short*)(ws + T_BYTES + AB_BYTES);
        convert_to_bf16<<<1920, 256, 0, stream>>>(seq, W, Abf, Wbf);
        dim3 g1(M_ / 64, N_ / 64, 1);            // 384 blocks, no split
        gemm_uv_bf16<<<g1, 256, 0, stream>>>(Abf, Wbf, bias, T);
        handshake_epilogue_quad<<<EGRID_, 192, 0, stream>>>(T, out);
    } else {
        dim3 g1(M_ / 64, N_ / 64);
        gemm_uv_mfma<<<g1, 256, 0, stream>>>(seq, W, bias, T);
        handshake_epilogue_quad<<<EGRID_, 192, 0, stream>>>(T, out);
    }
}